// Round 7
// baseline (324.193 us; speedup 1.0000x reference)
//
#include <hip/hip_runtime.h>
#include <math.h>

// x: (C,H,W) = (256,512,512) f32.  out = 2 * suffmax_W( suffmax_H( x ) )
// suffmax_W and suffmax_H commute -> scan W first (carry-independent), merge
// the H carry elementwise after ONE barrier per batch.
//
// W-split version: 2 blocks per channel (grid 512 -> 2 blocks/CU, 16 waves).
//   side 0 (blocks 0..255)   = RIGHT half, cols 256..511: producer. Publishes
//       per-row merged totals (its col-256 value = max over rows>=h, cols>=256)
//       to d_ws + a release flag per batch.
//   side 1 (blocks 256..511) = LEFT half, cols 0..255: consumer. Runs ~1 batch
//       behind, acquires the flag, merges the scalar row-total elementwise.
// Cross-block sync uses agent-scope atomics (cross-XCD safe). Producers have
// lower block indices -> they dispatch first -> no deadlock even without full
// co-residency.
constexpr int C     = 256;
constexpr int H     = 512;
constexpr int W     = 512;
constexpr int RPW   = 4;            // rows per wave per batch
constexpr int BATCH = 8 * RPW;      // 32 rows/batch
constexpr int NB    = H / BATCH;    // 16 batches
constexpr int HALF  = W / 2;        // 256 cols per side

typedef float v4f __attribute__((ext_vector_type(4)));

__device__ __forceinline__ v4f vmax4(v4f a, v4f b) {
    v4f r;
    r.x = fmaxf(a.x, b.x); r.y = fmaxf(a.y, b.y);
    r.z = fmaxf(a.z, b.z); r.w = fmaxf(a.w, b.w);
    return r;
}

__global__ void tlc_init(int* __restrict__ flg, int n) {
    int i = blockIdx.x * blockDim.x + threadIdx.x;
    if (i < n) flg[i] = 0;
}

// ---------------- W-split kernel: 512 blocks x 512 threads ----------------
__global__ __launch_bounds__(512, 4)   // 4 waves/SIMD -> VGPR <= 128
void tlc_split(const float* __restrict__ x, float* __restrict__ out,
               float* __restrict__ tot, int* __restrict__ flg) {
    const int bb   = blockIdx.x;
    const int side = bb >> 8;          // 0 = right/producer, 1 = left/consumer
    const int c    = bb & 255;
    const int tid  = threadIdx.x;
    const int g    = tid >> 6;         // wave 0..7
    const int lane = tid & 63;
    const int col  = (side == 0 ? HALF : 0) + lane * 4;  // 4 cols per lane

    __shared__ v4f ltot[2][8][64];     // wave column totals (double-buffered)
    __shared__ v4f gcol[2][64];        // running colmax (double-buffered)

    const float* __restrict__ xc   = x   + (size_t)c * H * W;
    float*       __restrict__ oc   = out + (size_t)c * H * W;
    float*       __restrict__ totc = tot + (size_t)c * H;
    int*         __restrict__ flgc = flg + (size_t)c * NB;

    const int s1  = min(lane + 1, 63),  s2  = min(lane + 2, 63);
    const int s4  = min(lane + 4, 63),  s8  = min(lane + 8, 63);
    const int s16 = min(lane + 16, 63), s32 = min(lane + 32, 63);

    if (g == 0) {
        const v4f ninf = (v4f){-INFINITY, -INFINITY, -INFINITY, -INFINITY};
        gcol[0][lane] = ninf;   // ordered before first read by batch-0 barrier
    }

    v4f b0[RPW], b1[RPW], b2[RPW];

#define LOADB(buf, t) {                                                      \
    const float* p0 = xc + (size_t)(H - BATCH * ((t) + 1) + RPW * g) * W + col; \
    _Pragma("unroll")                                                        \
    for (int r = 0; r < RPW; ++r)                                            \
        buf[r] = __builtin_nontemporal_load((const v4f*)(p0 + (size_t)r * W)); \
    }

#define STEPC(buf, t) {                                                      \
    const int rb = H - BATCH * ((t) + 1) + RPW * g;                          \
    const int pb = (t) & 1;                                                  \
    /* W suffix scan within the half, in place */                            \
    _Pragma("unroll")                                                        \
    for (int r = 0; r < RPW; ++r) {                                          \
        const v4f a = buf[r];                                                \
        const float u3 = a.w;                                                \
        const float u2 = fmaxf(a.z, u3);                                     \
        const float u1 = fmaxf(a.y, u2);                                     \
        const float u0 = fmaxf(a.x, u1);                                     \
        float e = __shfl(u0, s1);                                            \
        e = (lane == 63) ? -INFINITY : e;                                    \
        e = fmaxf(e, __shfl(e, s1));  e = fmaxf(e, __shfl(e, s2));           \
        e = fmaxf(e, __shfl(e, s4));  e = fmaxf(e, __shfl(e, s8));           \
        e = fmaxf(e, __shfl(e, s16)); e = fmaxf(e, __shfl(e, s32));          \
        buf[r] = (v4f){fmaxf(u0, e), fmaxf(u1, e), fmaxf(u2, e), fmaxf(u3, e)}; \
    }                                                                        \
    /* local H suffix chain */                                               \
    _Pragma("unroll")                                                        \
    for (int r = RPW - 2; r >= 0; --r) buf[r] = vmax4(buf[r], buf[r + 1]);   \
    ltot[pb][g][lane] = buf[0];                                              \
    __syncthreads();                                                         \
    v4f mA = gcol[pb][lane];                                                 \
    for (int gg = g + 1; gg < 8; ++gg) mA = vmax4(mA, ltot[pb][gg][lane]);   \
    if (g == 0) gcol[pb ^ 1][lane] = vmax4(buf[0], mA);                      \
    if (side == 0) {                                                         \
        /* producer: store right half + publish per-row totals + flag */     \
        _Pragma("unroll")                                                    \
        for (int r = 0; r < RPW; ++r) {                                      \
            const v4f m = vmax4(buf[r], mA);                                 \
            float* q = oc + (size_t)(rb + r) * W + col;                      \
            __builtin_nontemporal_store(m * 2.0f, (v4f*)q);                  \
            if (lane == 0)                                                   \
                __hip_atomic_store(&totc[rb + r], m.x, __ATOMIC_RELAXED,     \
                                   __HIP_MEMORY_SCOPE_AGENT);                \
        }                                                                    \
        __syncthreads();  /* drains vmcnt: totals performed before flag */   \
        if (tid == 0)                                                        \
            __hip_atomic_store(&flgc[(t)], 1, __ATOMIC_RELEASE,              \
                               __HIP_MEMORY_SCOPE_AGENT);                    \
    } else {                                                                 \
        /* consumer: wait for right half's totals, merge scalar per row */   \
        if (tid == 0) {                                                      \
            while (__hip_atomic_load(&flgc[(t)], __ATOMIC_ACQUIRE,           \
                                     __HIP_MEMORY_SCOPE_AGENT) == 0)         \
                __builtin_amdgcn_s_sleep(1);                                 \
        }                                                                    \
        __syncthreads();                                                     \
        _Pragma("unroll")                                                    \
        for (int r = 0; r < RPW; ++r) {                                      \
            const float rt = __hip_atomic_load(&totc[rb + r],                \
                                               __ATOMIC_RELAXED,             \
                                               __HIP_MEMORY_SCOPE_AGENT);    \
            v4f m = vmax4(buf[r], mA);                                       \
            m = vmax4(m, (v4f){rt, rt, rt, rt});                             \
            float* q = oc + (size_t)(rb + r) * W + col;                      \
            __builtin_nontemporal_store(m * 2.0f, (v4f*)q);                  \
        }                                                                    \
    } }

    // depth-2 pipeline, 3-buffer rotation, fully unrolled (NB = 16)
    LOADB(b0, 0)
    LOADB(b1, 1)

    LOADB(b2,  2)  STEPC(b0,  0)
    LOADB(b0,  3)  STEPC(b1,  1)
    LOADB(b1,  4)  STEPC(b2,  2)
    LOADB(b2,  5)  STEPC(b0,  3)
    LOADB(b0,  6)  STEPC(b1,  4)
    LOADB(b1,  7)  STEPC(b2,  5)
    LOADB(b2,  8)  STEPC(b0,  6)
    LOADB(b0,  9)  STEPC(b1,  7)
    LOADB(b1, 10)  STEPC(b2,  8)
    LOADB(b2, 11)  STEPC(b0,  9)
    LOADB(b0, 12)  STEPC(b1, 10)
    LOADB(b1, 13)  STEPC(b2, 11)
    LOADB(b2, 14)  STEPC(b0, 12)
    LOADB(b0, 15)  STEPC(b1, 13)
                   STEPC(b2, 14)
                   STEPC(b0, 15)

#undef LOADB
#undef STEPC
}

// ---------------- fallback: R6 single-block-per-channel kernel ------------
__global__ __launch_bounds__(512)
void tlc_fallback(const float* __restrict__ x, float* __restrict__ out) {
    const int tid  = threadIdx.x;
    const int g    = tid >> 6;
    const int lane = tid & 63;
    const int c    = blockIdx.x;
    const int col  = lane * 8;

    __shared__ v4f ltotA[2][8][64], ltotB[2][8][64];
    __shared__ v4f gcolA[2][64],    gcolB[2][64];

    const float* __restrict__ xc = x   + (size_t)c * H * W;
    float*       __restrict__ oc = out + (size_t)c * H * W;

    const int s1  = min(lane + 1, 63),  s2  = min(lane + 2, 63);
    const int s4  = min(lane + 4, 63),  s8  = min(lane + 8, 63);
    const int s16 = min(lane + 16, 63), s32 = min(lane + 32, 63);

    if (g == 0) {
        const v4f ninf = (v4f){-INFINITY, -INFINITY, -INFINITY, -INFINITY};
        gcolA[0][lane] = ninf;
        gcolB[0][lane] = ninf;
    }

    v4f b0A[RPW], b0B[RPW], b1A[RPW], b1B[RPW], b2A[RPW], b2B[RPW];

#define LOADB(bufA, bufB, t) {                                               \
    const float* p0 = xc + (size_t)(H - BATCH * ((t) + 1) + RPW * g) * W + col; \
    _Pragma("unroll")                                                        \
    for (int r = 0; r < RPW; ++r) {                                          \
        bufA[r] = __builtin_nontemporal_load((const v4f*)(p0 + (size_t)r * W));     \
        bufB[r] = __builtin_nontemporal_load((const v4f*)(p0 + (size_t)r * W + 4)); \
    } }

#define STEPC(bufA, bufB, t) {                                               \
    const int rb = H - BATCH * ((t) + 1) + RPW * g;                          \
    const int pb = (t) & 1;                                                  \
    _Pragma("unroll")                                                        \
    for (int r = 0; r < RPW; ++r) {                                          \
        const v4f a = bufA[r], b = bufB[r];                                  \
        const float u7 = b.w;                                                \
        const float u6 = fmaxf(b.z, u7);                                     \
        const float u5 = fmaxf(b.y, u6);                                     \
        const float u4 = fmaxf(b.x, u5);                                     \
        const float u3 = fmaxf(a.w, u4);                                     \
        const float u2 = fmaxf(a.z, u3);                                     \
        const float u1 = fmaxf(a.y, u2);                                     \
        const float u0 = fmaxf(a.x, u1);                                     \
        float e = __shfl(u0, s1);                                            \
        e = (lane == 63) ? -INFINITY : e;                                    \
        e = fmaxf(e, __shfl(e, s1));  e = fmaxf(e, __shfl(e, s2));           \
        e = fmaxf(e, __shfl(e, s4));  e = fmaxf(e, __shfl(e, s8));           \
        e = fmaxf(e, __shfl(e, s16)); e = fmaxf(e, __shfl(e, s32));          \
        bufA[r] = (v4f){fmaxf(u0, e), fmaxf(u1, e), fmaxf(u2, e), fmaxf(u3, e)}; \
        bufB[r] = (v4f){fmaxf(u4, e), fmaxf(u5, e), fmaxf(u6, e), fmaxf(u7, e)}; \
    }                                                                        \
    _Pragma("unroll")                                                        \
    for (int r = RPW - 2; r >= 0; --r) {                                     \
        bufA[r] = vmax4(bufA[r], bufA[r + 1]);                               \
        bufB[r] = vmax4(bufB[r], bufB[r + 1]);                               \
    }                                                                        \
    ltotA[pb][g][lane] = bufA[0];                                            \
    ltotB[pb][g][lane] = bufB[0];                                            \
    __syncthreads();                                                         \
    v4f mA = gcolA[pb][lane];                                                \
    v4f mB = gcolB[pb][lane];                                                \
    for (int gg = g + 1; gg < 8; ++gg) {                                     \
        mA = vmax4(mA, ltotA[pb][gg][lane]);                                 \
        mB = vmax4(mB, ltotB[pb][gg][lane]);                                 \
    }                                                                        \
    if (g == 0) {                                                            \
        gcolA[pb ^ 1][lane] = vmax4(bufA[0], mA);                            \
        gcolB[pb ^ 1][lane] = vmax4(bufB[0], mB);                            \
    }                                                                        \
    _Pragma("unroll")                                                        \
    for (int r = 0; r < RPW; ++r) {                                          \
        v4f oA = vmax4(bufA[r], mA) * 2.0f;                                  \
        v4f oB = vmax4(bufB[r], mB) * 2.0f;                                  \
        float* q = oc + (size_t)(rb + r) * W + col;                          \
        __builtin_nontemporal_store(oA, (v4f*)q);                            \
        __builtin_nontemporal_store(oB, (v4f*)(q + 4));                      \
    } }

    LOADB(b0A, b0B, 0)
    LOADB(b1A, b1B, 1)

    LOADB(b2A, b2B,  2)  STEPC(b0A, b0B,  0)
    LOADB(b0A, b0B,  3)  STEPC(b1A, b1B,  1)
    LOADB(b1A, b1B,  4)  STEPC(b2A, b2B,  2)
    LOADB(b2A, b2B,  5)  STEPC(b0A, b0B,  3)
    LOADB(b0A, b0B,  6)  STEPC(b1A, b1B,  4)
    LOADB(b1A, b1B,  7)  STEPC(b2A, b2B,  5)
    LOADB(b2A, b2B,  8)  STEPC(b0A, b0B,  6)
    LOADB(b0A, b0B,  9)  STEPC(b1A, b1B,  7)
    LOADB(b1A, b1B, 10)  STEPC(b2A, b2B,  8)
    LOADB(b2A, b2B, 11)  STEPC(b0A, b0B,  9)
    LOADB(b0A, b0B, 12)  STEPC(b1A, b1B, 10)
    LOADB(b1A, b1B, 13)  STEPC(b2A, b2B, 11)
    LOADB(b2A, b2B, 14)  STEPC(b0A, b0B, 12)
    LOADB(b0A, b0B, 15)  STEPC(b1A, b1B, 13)
                         STEPC(b2A, b2B, 14)
                         STEPC(b0A, b0B, 15)

#undef LOADB
#undef STEPC
}

extern "C" void kernel_launch(void* const* d_in, const int* in_sizes, int n_in,
                              void* d_out, int out_size, void* d_ws, size_t ws_size,
                              hipStream_t stream) {
    const float* x   = (const float*)d_in[0];
    float*       out = (float*)d_out;

    const size_t needTot = (size_t)C * H * sizeof(float);   // 512 KB
    const size_t needFlg = (size_t)C * NB * sizeof(int);    // 16 KB

    if (ws_size >= needTot + needFlg) {
        float* tot = (float*)d_ws;
        int*   flg = (int*)((char*)d_ws + needTot);
        const int nflags = C * NB;
        tlc_init<<<dim3((nflags + 255) / 256), dim3(256), 0, stream>>>(flg, nflags);
        tlc_split<<<dim3(2 * C), dim3(512), 0, stream>>>(x, out, tot, flg);
    } else {
        tlc_fallback<<<dim3(C), dim3(512), 0, stream>>>(x, out);
    }
}

// Round 8
// 110.844 us; speedup vs baseline: 2.9248x; 2.9248x over previous
//
#include <hip/hip_runtime.h>
#include <math.h>

// x: (C,H,W) = (256,512,512) f32.  out = 2 * suffmax_W( suffmax_H( x ) )
// suffmax_W and suffmax_H commute -> scan W first (carry-independent), merge
// the H carry elementwise after ONE barrier per batch.
//
// Cache policy (R8): PLAIN loads so the 256 MB input allocates in the 256 MB
// Infinity Cache and stays resident across graph replays (R4 evidence:
// FETCH_SIZE = 131 MB = half the input with plain loads); NONTEMPORAL stores
// so the 256 MB output does NOT allocate and evict the input.
constexpr int C     = 256;
constexpr int H     = 512;
constexpr int W     = 512;
constexpr int RPW   = 4;            // rows per wave per batch (VGPR-safe)
constexpr int BATCH = 8 * RPW;      // 32 rows/batch
constexpr int NB    = H / BATCH;    // 16 batches

typedef float v4f __attribute__((ext_vector_type(4)));

__device__ __forceinline__ v4f vmax4(v4f a, v4f b) {
    v4f r;
    r.x = fmaxf(a.x, b.x); r.y = fmaxf(a.y, b.y);
    r.z = fmaxf(a.z, b.z); r.w = fmaxf(a.w, b.w);
    return r;
}

// One 512-thread block per channel; lane owns 8 consecutive columns so the
// 512-col W suffix scan is one wave (7 in-lane fmax + 7 shuffles). Each wave
// owns 4 rows/batch. 16 batches fully unrolled with a 3-buffer rotation:
// while computing batch t, loads for t+1 and t+2 are in flight (no register
// copies -> no vmcnt(0) drain at batch boundaries).
__global__ __launch_bounds__(512)
void tlc_kernel(const float* __restrict__ x, float* __restrict__ out) {
    const int tid  = threadIdx.x;
    const int g    = tid >> 6;        // wave 0..7
    const int lane = tid & 63;
    const int c    = blockIdx.x;
    const int col  = lane * 8;        // first of this lane's 8 columns

    __shared__ v4f ltotA[2][8][64], ltotB[2][8][64];  // wave column totals
    __shared__ v4f gcolA[2][64],    gcolB[2][64];     // running colmax

    const float* __restrict__ xc = x   + (size_t)c * H * W;
    float*       __restrict__ oc = out + (size_t)c * H * W;

    const int s1  = min(lane + 1, 63),  s2  = min(lane + 2, 63);
    const int s4  = min(lane + 4, 63),  s8  = min(lane + 8, 63);
    const int s16 = min(lane + 16, 63), s32 = min(lane + 32, 63);

    if (g == 0) {
        const v4f ninf = (v4f){-INFINITY, -INFINITY, -INFINITY, -INFINITY};
        gcolA[0][lane] = ninf;   // ordered before first read by batch-0 barrier
        gcolB[0][lane] = ninf;
    }

    v4f b0A[RPW], b0B[RPW], b1A[RPW], b1B[RPW], b2A[RPW], b2B[RPW];

// issue batch t's loads into buffer `buf` (PLAIN loads -> LLC-allocating)
#define LOADB(bufA, bufB, t) {                                               \
    const float* p0 = xc + (size_t)(H - BATCH * ((t) + 1) + RPW * g) * W + col; \
    _Pragma("unroll")                                                        \
    for (int r = 0; r < RPW; ++r) {                                          \
        bufA[r] = *(const v4f*)(p0 + (size_t)r * W);                         \
        bufB[r] = *(const v4f*)(p0 + (size_t)r * W + 4);                     \
    } }

// consume buffer = batch t: W-scan in place, local H chain, publish totals,
// ONE barrier, elementwise carry merge, nontemporal store.
#define STEPC(bufA, bufB, t) {                                               \
    const int rb = H - BATCH * ((t) + 1) + RPW * g;                          \
    const int pb = (t) & 1;                                                  \
    _Pragma("unroll")                                                        \
    for (int r = 0; r < RPW; ++r) {                                          \
        const v4f a = bufA[r], b = bufB[r];                                  \
        const float u7 = b.w;                                                \
        const float u6 = fmaxf(b.z, u7);                                     \
        const float u5 = fmaxf(b.y, u6);                                     \
        const float u4 = fmaxf(b.x, u5);                                     \
        const float u3 = fmaxf(a.w, u4);                                     \
        const float u2 = fmaxf(a.z, u3);                                     \
        const float u1 = fmaxf(a.y, u2);                                     \
        const float u0 = fmaxf(a.x, u1);                                     \
        float e = __shfl(u0, s1);                                            \
        e = (lane == 63) ? -INFINITY : e;                                    \
        e = fmaxf(e, __shfl(e, s1));  e = fmaxf(e, __shfl(e, s2));           \
        e = fmaxf(e, __shfl(e, s4));  e = fmaxf(e, __shfl(e, s8));           \
        e = fmaxf(e, __shfl(e, s16)); e = fmaxf(e, __shfl(e, s32));          \
        bufA[r] = (v4f){fmaxf(u0, e), fmaxf(u1, e), fmaxf(u2, e), fmaxf(u3, e)}; \
        bufB[r] = (v4f){fmaxf(u4, e), fmaxf(u5, e), fmaxf(u6, e), fmaxf(u7, e)}; \
    }                                                                        \
    _Pragma("unroll")                                                        \
    for (int r = RPW - 2; r >= 0; --r) {                                     \
        bufA[r] = vmax4(bufA[r], bufA[r + 1]);                               \
        bufB[r] = vmax4(bufB[r], bufB[r + 1]);                               \
    }                                                                        \
    ltotA[pb][g][lane] = bufA[0];                                            \
    ltotB[pb][g][lane] = bufB[0];                                            \
    __syncthreads();                                                         \
    v4f mA = gcolA[pb][lane];                                                \
    v4f mB = gcolB[pb][lane];                                                \
    for (int gg = g + 1; gg < 8; ++gg) {                                     \
        mA = vmax4(mA, ltotA[pb][gg][lane]);                                 \
        mB = vmax4(mB, ltotB[pb][gg][lane]);                                 \
    }                                                                        \
    if (g == 0) {                                                            \
        gcolA[pb ^ 1][lane] = vmax4(bufA[0], mA);                            \
        gcolB[pb ^ 1][lane] = vmax4(bufB[0], mB);                            \
    }                                                                        \
    _Pragma("unroll")                                                        \
    for (int r = 0; r < RPW; ++r) {                                          \
        v4f oA = vmax4(bufA[r], mA) * 2.0f;                                  \
        v4f oB = vmax4(bufB[r], mB) * 2.0f;                                  \
        float* q = oc + (size_t)(rb + r) * W + col;                          \
        __builtin_nontemporal_store(oA, (v4f*)q);                            \
        __builtin_nontemporal_store(oB, (v4f*)(q + 4));                      \
    } }

    // depth-2 pipeline, 3-buffer rotation, fully unrolled (NB = 16)
    LOADB(b0A, b0B, 0)
    LOADB(b1A, b1B, 1)

    LOADB(b2A, b2B,  2)  STEPC(b0A, b0B,  0)
    LOADB(b0A, b0B,  3)  STEPC(b1A, b1B,  1)
    LOADB(b1A, b1B,  4)  STEPC(b2A, b2B,  2)
    LOADB(b2A, b2B,  5)  STEPC(b0A, b0B,  3)
    LOADB(b0A, b0B,  6)  STEPC(b1A, b1B,  4)
    LOADB(b1A, b1B,  7)  STEPC(b2A, b2B,  5)
    LOADB(b2A, b2B,  8)  STEPC(b0A, b0B,  6)
    LOADB(b0A, b0B,  9)  STEPC(b1A, b1B,  7)
    LOADB(b1A, b1B, 10)  STEPC(b2A, b2B,  8)
    LOADB(b2A, b2B, 11)  STEPC(b0A, b0B,  9)
    LOADB(b0A, b0B, 12)  STEPC(b1A, b1B, 10)
    LOADB(b1A, b1B, 13)  STEPC(b2A, b2B, 11)
    LOADB(b2A, b2B, 14)  STEPC(b0A, b0B, 12)
    LOADB(b0A, b0B, 15)  STEPC(b1A, b1B, 13)
                         STEPC(b2A, b2B, 14)
                         STEPC(b0A, b0B, 15)

#undef LOADB
#undef STEPC
}

extern "C" void kernel_launch(void* const* d_in, const int* in_sizes, int n_in,
                              void* d_out, int out_size, void* d_ws, size_t ws_size,
                              hipStream_t stream) {
    const float* x   = (const float*)d_in[0];
    float*       out = (float*)d_out;
    tlc_kernel<<<dim3(C), dim3(512), 0, stream>>>(x, out);
}